// Round 7
// baseline (358.157 us; speedup 1.0000x reference)
//
#include <hip/hip_runtime.h>
#include <cstdint>
#include <math.h>

// GREEN since r6. Ladder: r15 490 -> r17 326 (pk_fma full-rate) -> r19 285
// (DPP butterfly). r20 keep-alive NEUTRAL; r21 LDS-launder NEUTRAL (VGPR
// stuck 120): store-to-load forwarding folded the ds_reads back to global
// loads (same-thread staging) -> U streamed from memory every step in ALL
// prior rounds. Bandwidth check: 48KB/wave/step x 8 waves/CU ~= 50 TB/s of
// U re-reads -> partly BW/latency bound, unfixable at 2 chains/wave.
// THIS ROUND r22 (restructure):
//  - CPB=4 chains/wave, 4 waves/block (256 thr), 256 blocks, 1 wave/SIMD,
//    all-resident. Each U-pair read feeds 4 chains (2 pk groups) -> per-CU
//    U demand halves.
//  - U staged to 48KB LDS with lane-XOR writer permutation (slot for lane j
//    written by lane j^1: cross-thread => forwarding impossible), then
//    bulk-loaded to v4f uqr[48] (192 floats, const-indexed) + in-loop asm
//    memory clobber => remat AND re-read both illegal => RA must allocate.
//    __launch_bounds__(256,1) -> 512-reg budget; ask ~330.
//  - gumbels in 2x72-step halves (restage at t=72, barrier-protected) to
//    fit 63.6KB static LDS (<64KB limit).
//  - per-chain arithmetic/PRNG/FMA-order bit-identical (partitionable
//    threefry survives re-blocking) -> absmax must stay 0.0.
// DIAGNOSTIC: VGPR ~300+ = residency -> predict 100-160us. VGPR ~120-160 =
// spill -> 200-300us (next: 2 gates in regs). >=300us = latency exposure
// (next: 2 waves/SIMD + CPB=4 dot).
// Locked-in: PRNG = partitionable threefry (key_t = tf((0,42),(0,t)); bits =
// o0^o1 of tf(key_t,(0,2s+cat))); f32 in/out; decisions rounding-robust.

#define NSAMP 4096
#define NSTEP 144
#define HID 64
#define CPW 4              // chains per wave
#define WPB 4              // waves per block
#define CPBLK (CPW * WPB)  // 16 chains per block
#define HSTEP 72           // gumbel half-window (steps)

typedef float v4f __attribute__((ext_vector_type(4)));
typedef float v2f __attribute__((ext_vector_type(2)));

// ---- JAX threefry2x32 (20 rounds, key-inject every 4) ----
__device__ __forceinline__ void threefry2x32(uint32_t k0, uint32_t k1,
                                             uint32_t x0, uint32_t x1,
                                             uint32_t& o0, uint32_t& o1) {
  const uint32_t ks0 = k0, ks1 = k1, ks2 = k0 ^ k1 ^ 0x1BD11BDAu;
  x0 += ks0; x1 += ks1;
#define TF_ROUND(d) { x0 += x1; x1 = (x1 << (d)) | (x1 >> (32 - (d))); x1 ^= x0; }
  TF_ROUND(13) TF_ROUND(15) TF_ROUND(26) TF_ROUND(6)
  x0 += ks1; x1 += ks2 + 1u;
  TF_ROUND(17) TF_ROUND(29) TF_ROUND(16) TF_ROUND(24)
  x0 += ks2; x1 += ks0 + 2u;
  TF_ROUND(13) TF_ROUND(15) TF_ROUND(26) TF_ROUND(6)
  x0 += ks0; x1 += ks1 + 3u;
  TF_ROUND(17) TF_ROUND(29) TF_ROUND(16) TF_ROUND(24)
  x0 += ks1; x1 += ks2 + 4u;
  TF_ROUND(13) TF_ROUND(15) TF_ROUND(26) TF_ROUND(6)
  x0 += ks2; x1 += ks0 + 5u;
#undef TF_ROUND
  o0 = x0; o1 = x1;
}

__device__ __forceinline__ float fsig(float x) {        // 1/(1+e^-x), stable
  return __builtin_amdgcn_rcpf(1.0f + __expf(-x));
}
__device__ __forceinline__ float ftanh(float x) {       // 1 - 2/(e^2x+1)
  const float e = __expf(2.0f * x);
  return 1.0f - 2.0f * __builtin_amdgcn_rcpf(e + 1.0f);
}

// Packed f32 FMA, one chain-pair in (lo,hi). u-pair even-aligned; LO
// broadcasts its low element to both halves, HI the high one.
#define PKFMA_LO(acc, h2, up) \
  asm("v_pk_fma_f32 %0, %1, %2, %0 op_sel_hi:[1,0,1]" \
      : "+v"(acc) : "v"(h2), "v"(up));
#define PKFMA_HI(acc, h2, up) \
  asm("v_pk_fma_f32 %0, %1, %2, %0 op_sel:[0,1,0] op_sel_hi:[1,1,1]" \
      : "+v"(acc) : "v"(h2), "v"(up));

// DPP butterfly level: v += lane-swapped(v); bitwise == __shfl_xor(v,m)
// given the uniformity at each level (proven r19).
template <int CTRL>
__device__ __forceinline__ float dpp_add(float v) {
  union { float f; int i; } c; c.f = v;
  union { int i; float f; } r;
  r.i = __builtin_amdgcn_mov_dpp(c.i, CTRL, 0xF, 0xF, true);
  return v + r.f;
}
#define DPP_XOR1 0xB1
#define DPP_XOR2 0x4E
#define DPP_XOR4 0x141
#define DPP_XOR8 0x140

__global__ __launch_bounds__(256, 1) void vmc_kernel(
    const float* __restrict__ W, const float* __restrict__ U,
    const float* __restrict__ B, const float* __restrict__ Wd,
    const float* __restrict__ Bd, float* __restrict__ out) {
  const int tid = threadIdx.x;
  const int j = tid & 63;              // hidden unit owned by this lane
  const int w = tid >> 6;              // wave id in block
  const int s_blk = blockIdx.x * CPBLK;
  const int s0 = s_blk + w * CPW;      // first chain of this wave

  __shared__ __align__(16) float4 uq4[3 * 16 * 64];       // 48KB U pre-packed
  __shared__ __align__(16) float4 hsh4[WPB * HID];        // 4KB h {a,b,c,d}
  __shared__ __align__(16) uint2 kkeys[NSTEP];            // 1.15KB
  __shared__ __align__(16) float gsh[CPBLK * 2 * HSTEP];  // 9KB gumbel half

  // --- phase 0: per-step keys ---
  for (int t = tid; t < NSTEP; t += 256) {
    uint32_t o0, o1;
    threefry2x32(0u, 42u, 0u, (uint32_t)t, o0, o1);
    kkeys[t].x = o0; kkeys[t].y = o1;
  }
  __syncthreads();

  // --- phase 1a: U -> uq4, lane-XOR writer (cross-thread, no forwarding).
  // slot v = g*1024 + q*64 + lane holds {U[4q+e][g*64+lane]}, e=0..3 ---
  for (int vv = tid; vv < 3 * 16 * 64; vv += 256) {
    const int v = (vv & ~63) | ((vv ^ 1) & 63);
    const int g = v >> 10, rem = v & 1023, q = rem >> 6;
    const int col = (g << 6) | (rem & 63);
    float4 x;
    x.x = U[(4 * q + 0) * 192 + col];
    x.y = U[(4 * q + 1) * 192 + col];
    x.z = U[(4 * q + 2) * 192 + col];
    x.w = U[(4 * q + 3) * 192 + col];
    uq4[v] = x;
  }

  // --- phase 1b: gumbels, EXACT path (f64 libm). Half TB..TB+71. ---
#define STAGE_GSH(TB) \
  for (int id = tid; id < CPBLK * 2 * HSTEP; id += 256) { \
    const int c16 = id / 144, r = id - c16 * 144; \
    const uint2 kt = kkeys[(TB) + (r >> 1)]; \
    const uint32_t i = 2u * (uint32_t)(s_blk + c16) + (uint32_t)(r & 1); \
    uint32_t o0, o1; \
    threefry2x32(kt.x, kt.y, 0u, i, o0, o1); \
    const uint32_t bits = o0 ^ o1; \
    union { uint32_t u; float f; } cv; cv.u = (bits >> 9) | 0x3F800000u; \
    float uf = cv.f - 1.0f; \
    uf = fmaxf(uf, 1.17549435e-38f); \
    const float inner = (float)log((double)uf); \
    gsh[id] = -(float)log((double)(-inner)); \
  }
  STAGE_GSH(0)
  __syncthreads();

  // --- bulk-load this lane's U columns into 48 v4f regs (192 floats).
  // Const-indexed; sources are cross-thread LDS -> not remattable past the
  // in-loop clobber => true residency or visible spill. ---
  v4f uqr[48];
#pragma unroll
  for (int g = 0; g < 3; ++g)
#pragma unroll
    for (int q = 0; q < 16; ++q)
      uqr[g * 16 + q] = *(const v4f*)&uq4[g * 1024 + q * 64 + j];

  const float b1z = B[192 + j], b1r = B[256 + j], b1n = B[320 + j];
  const float b0z = B[j], b0r = B[64 + j], b0n = B[128 + j];
  const float xW0z = W[j] + b0z,        xW1z = W[192 + j] + b0z;
  const float xW0r = W[64 + j] + b0r,   xW1r = W[256 + j] + b0r;
  const float xW0n = W[128 + j] + b0n,  xW1n = W[320 + j] + b0n;
  const float wdd = Wd[2 * j + 1] - Wd[2 * j];
  const float bdd = Bd[1] - Bd[0];

  const float4* hw = &hsh4[w * HID];
  float4* hww = &hsh4[w * HID];
  const float* gw = &gsh[(w * CPW) * (2 * HSTEP)];

  float axz[4], axr[4], axn[4], logP[4], hcur[4];
#pragma unroll
  for (int cc = 0; cc < 4; ++cc) {
    axz[cc] = b0z; axr[cc] = b0r; axn[cc] = b0n;
    logP[cc] = 0.0f; hcur[cc] = 0.0f;
  }
  v2f hzAB = {0.f, 0.f}, hzCD = {0.f, 0.f};
  v2f hrAB = {0.f, 0.f}, hrCD = {0.f, 0.f};
  v2f hnAB = {0.f, 0.f}, hnCD = {0.f, 0.f};

#pragma unroll 1
  for (int t = 0; t < NSTEP; ++t) {
    // clobber: forbids remat/re-read of uqr sources + any load sinking
    asm volatile("" ::: "memory");
    if (t == HSTEP) {           // uniform branch: restage gumbel half 1
      __syncthreads();
      STAGE_GSH(HSTEP)
      __syncthreads();
    }

    // ---- gates from PREVIOUS dot (software pipeline), per chain ----
#define GATE(cc, hz_, hr_, hn_) { \
      const float az = axz[cc] + ((hz_) + b1z), ar = axr[cc] + ((hr_) + b1r); \
      const float zz = fsig(az), rr = fsig(ar); \
      const float hh = ftanh(axn[cc] + rr * ((hn_) + b1n)); \
      hcur[cc] = zz * hcur[cc] + (1.0f - zz) * hh; }
    GATE(0, hzAB.x, hrAB.x, hnAB.x)
    GATE(1, hzAB.y, hrAB.y, hnAB.y)
    GATE(2, hzCD.x, hrCD.x, hnCD.x)
    GATE(3, hzCD.y, hrCD.y, hnCD.y)
#undef GATE
    hww[j] = make_float4(hcur[0], hcur[1], hcur[2], hcur[3]);

    // ---- dense difference-reduction + decision, per chain (bit-exact) ----
    const int dt = (t < HSTEP) ? t : (t - HSTEP);
    const float* gt = gw + 2 * dt;
    int smv[4];
#define CHAIN_DEC(cc) { \
      float d_ = hcur[cc] * wdd; \
      d_ = dpp_add<DPP_XOR1>(d_); d_ = dpp_add<DPP_XOR2>(d_); \
      d_ = dpp_add<DPP_XOR4>(d_); d_ = dpp_add<DPP_XOR8>(d_); \
      d_ += __shfl_xor(d_, 16, 64); d_ += __shfl_xor(d_, 32, 64); \
      const float d = d_ + bdd; \
      const float p1 = fsig(d), p0 = fsig(-d); \
      const float lp0 = __logf(1e-10f + p0); \
      const float lp1 = __logf(1e-10f + p1); \
      const float g0 = gt[(cc) * 144], g1 = gt[(cc) * 144 + 1]; \
      const int sm = (lp1 + g1) > (lp0 + g0); \
      logP[cc] += sm ? lp1 : lp0; \
      axz[cc] = sm ? xW1z : xW0z; \
      axr[cc] = sm ? xW1r : xW0r; \
      axn[cc] = sm ? xW1n : xW0n; \
      smv[cc] = sm; }
    CHAIN_DEC(0) CHAIN_DEC(1) CHAIN_DEC(2) CHAIN_DEC(3)
#undef CHAIN_DEC
    if (j == 0) {
      out[(s0 + 0) * NSTEP + t] = smv[0] ? 1.0f : 0.0f;
      out[(s0 + 1) * NSTEP + t] = smv[1] ? 1.0f : 0.0f;
      out[(s0 + 2) * NSTEP + t] = smv[2] ? 1.0f : 0.0f;
      out[(s0 + 3) * NSTEP + t] = smv[3] ? 1.0f : 0.0f;
    }

    // ---- dot for NEXT step: hm = h_t @ U. h float4 {a,b,c,d} broadcast
    // from LDS (.xy/.zw are even-aligned pk operands); U from uqr regs.
    // Per-accumulator k-ascending order identical to r21 -> bit-exact. ----
    hzAB = v2f{0.f, 0.f}; hzCD = v2f{0.f, 0.f};
    hrAB = v2f{0.f, 0.f}; hrCD = v2f{0.f, 0.f};
    hnAB = v2f{0.f, 0.f}; hnCD = v2f{0.f, 0.f};
#define SV2(x, a, b) __builtin_shufflevector(x, x, a, b)
#define DOTC(c_) { \
      const v4f uz4 = uqr[(c_)]; \
      const v4f ur4 = uqr[16 + (c_)]; \
      const v4f un4 = uqr[32 + (c_)]; \
      const v4f h40 = *(const v4f*)&hw[(c_) * 4 + 0]; \
      const v4f h41 = *(const v4f*)&hw[(c_) * 4 + 1]; \
      const v4f h42 = *(const v4f*)&hw[(c_) * 4 + 2]; \
      const v4f h43 = *(const v4f*)&hw[(c_) * 4 + 3]; \
      const v2f uz01 = SV2(uz4, 0, 1), uz23 = SV2(uz4, 2, 3); \
      const v2f ur01 = SV2(ur4, 0, 1), ur23 = SV2(ur4, 2, 3); \
      const v2f un01 = SV2(un4, 0, 1), un23 = SV2(un4, 2, 3); \
      { const v2f hab = SV2(h40, 0, 1), hcd = SV2(h40, 2, 3); \
        PKFMA_LO(hzAB, hab, uz01) PKFMA_LO(hzCD, hcd, uz01) \
        PKFMA_LO(hrAB, hab, ur01) PKFMA_LO(hrCD, hcd, ur01) \
        PKFMA_LO(hnAB, hab, un01) PKFMA_LO(hnCD, hcd, un01) } \
      { const v2f hab = SV2(h41, 0, 1), hcd = SV2(h41, 2, 3); \
        PKFMA_HI(hzAB, hab, uz01) PKFMA_HI(hzCD, hcd, uz01) \
        PKFMA_HI(hrAB, hab, ur01) PKFMA_HI(hrCD, hcd, ur01) \
        PKFMA_HI(hnAB, hab, un01) PKFMA_HI(hnCD, hcd, un01) } \
      { const v2f hab = SV2(h42, 0, 1), hcd = SV2(h42, 2, 3); \
        PKFMA_LO(hzAB, hab, uz23) PKFMA_LO(hzCD, hcd, uz23) \
        PKFMA_LO(hrAB, hab, ur23) PKFMA_LO(hrCD, hcd, ur23) \
        PKFMA_LO(hnAB, hab, un23) PKFMA_LO(hnCD, hcd, un23) } \
      { const v2f hab = SV2(h43, 0, 1), hcd = SV2(h43, 2, 3); \
        PKFMA_HI(hzAB, hab, uz23) PKFMA_HI(hzCD, hcd, uz23) \
        PKFMA_HI(hrAB, hab, ur23) PKFMA_HI(hrCD, hcd, ur23) \
        PKFMA_HI(hnAB, hab, un23) PKFMA_HI(hnCD, hcd, un23) } }
    DOTC(0)  DOTC(1)  DOTC(2)  DOTC(3)
    DOTC(4)  DOTC(5)  DOTC(6)  DOTC(7)
    DOTC(8)  DOTC(9)  DOTC(10) DOTC(11)
    DOTC(12) DOTC(13) DOTC(14) DOTC(15)
#undef DOTC
#undef SV2
  }

  if (j == 0) {
    *(float4*)&out[NSAMP * NSTEP + s0] =
        make_float4(logP[0], logP[1], logP[2], logP[3]);
  }
}

extern "C" void kernel_launch(void* const* d_in, const int* in_sizes, int n_in,
                              void* d_out, int out_size, void* d_ws, size_t ws_size,
                              hipStream_t stream) {
  // inputs (setup_inputs order): nsamples(1), W(2x192), U(64x192), b(2x192),
  // Wd(64x2), bd(2) — float32
  const float* W  = (const float*)d_in[1];
  const float* U  = (const float*)d_in[2];
  const float* B  = (const float*)d_in[3];
  const float* Wd = (const float*)d_in[4];
  const float* Bd = (const float*)d_in[5];
  vmc_kernel<<<dim3(NSAMP / CPBLK), dim3(WPB * HID), 0, stream>>>(
      W, U, B, Wd, Bd, (float*)d_out);
}